// Round 10
// baseline (191.540 us; speedup 1.0000x reference)
//
#include <hip/hip_runtime.h>
#include <hip/hip_cooperative_groups.h>

namespace cg = cooperative_groups;

#define LN_EPS 1e-5f

__device__ __forceinline__ float dot8(float4 a0, float4 a1, float4 b0, float4 b1) {
    return a0.x * b0.x + a0.y * b0.y + a0.z * b0.z + a0.w * b0.w +
           a1.x * b1.x + a1.y * b1.y + a1.z * b1.z + a1.w * b1.w;
}

// ---------------------------------------------------------------------------
// k12: R6-proven structure (phases 1+2, ONE grid.sync, nothing but msaR
// crosses it — R9 showed grid.sync flushes L2 across XCDs, so staged data
// must be minimal). Change vs R6: proj+LN fused in both phases via 16-lane
// in-wave reductions (thread layout r=tid>>4, cB=tid&15) — removes 2
// barriers + 2 LDS round-trips. LDS 30.2 KB -> 2 blocks/CU co-residency.
// ---------------------------------------------------------------------------
__global__ __launch_bounds__(512, 4) void k12(
    const float* __restrict__ ctcf, const float* __restrict__ hac,
    const float* __restrict__ me1,  const float* __restrict__ me3,
    const float* __restrict__ ew,   const float* __restrict__ eb,
    const float* __restrict__ pe,
    const float* __restrict__ riw,  const float* __restrict__ rib,
    const float* __restrict__ row_w,const float* __restrict__ row_b,
    const float* __restrict__ rlg,  const float* __restrict__ rlb,
    const float* __restrict__ ciw,  const float* __restrict__ cib,
    const float* __restrict__ cow,  const float* __restrict__ cob,
    const float* __restrict__ clg,  const float* __restrict__ clb,
    float* msaR, float* mbuf, float* nbuf)
{
    __shared__ float smem[7552];     // 30.2 KB
    const int bx  = blockIdx.x;      // 0..511
    const int tid = threadIdx.x;     // 0..511
    cg::grid_group grid = cg::this_grid();

    // ================= Phase 1: row attention =================
    {
        float* sqkv = smem;          // [64*100]
        float* so   = smem + 6400;   // [32][36]

        const int qh = bx & 1, s = (bx >> 1) & 3, b = bx >> 3;
        const int bs = b * 4 + s;
        const int qbase = qh * 32;
        const float* chip = (s == 0) ? ctcf : (s == 1) ? hac : (s == 2) ? me1 : me3;
        const int l   = tid & 63;
        const int cgi = __builtin_amdgcn_readfirstlane(tid >> 6);

        // fused embed into registers
        float xr[32];
        {
            const float cv = chip[b * 64 + l];
            const float4* pe4 = (const float4*)&pe[l * 32];
            const float4* ew4 = (const float4*)ew;
            const float4* eb4 = (const float4*)eb;
#pragma unroll
            for (int c4 = 0; c4 < 8; ++c4) {
                float4 pv = pe4[c4], e = ew4[c4], bb = eb4[c4];
                xr[c4 * 4 + 0] = cv * e.x + bb.x + pv.x;
                xr[c4 * 4 + 1] = cv * e.y + bb.y + pv.y;
                xr[c4 * 4 + 2] = cv * e.z + bb.z + pv.z;
                xr[c4 * 4 + 3] = cv * e.w + bb.w + pv.w;
            }
        }

        // QKV: contiguous 12-col chunk per wave -> 3 ds_write_b128
        {
            const int cc0 = cgi * 12;
            float acc[12];
#pragma unroll
            for (int ii = 0; ii < 12; ++ii) acc[ii] = rib[cc0 + ii];
#pragma unroll
            for (int ii = 0; ii < 12; ++ii) {
                const float4* wr4 = (const float4*)&riw[(cc0 + ii) * 32];
#pragma unroll
                for (int c4 = 0; c4 < 8; ++c4) {
                    float4 wv = wr4[c4];
                    acc[ii] += xr[c4 * 4 + 0] * wv.x + xr[c4 * 4 + 1] * wv.y +
                               xr[c4 * 4 + 2] * wv.z + xr[c4 * 4 + 3] * wv.w;
                }
            }
            float* dst = &sqkv[l * 100 + cc0];
            *(float4*)(dst + 0) = make_float4(acc[0], acc[1], acc[2],  acc[3]);
            *(float4*)(dst + 4) = make_float4(acc[4], acc[5], acc[6],  acc[7]);
            *(float4*)(dst + 8) = make_float4(acc[8], acc[9], acc[10], acc[11]);
        }
        __syncthreads();

        // attention, two-pass: thread (h = tid>>7, q = (tid>>2)&31, kc = tid&3)
        {
            const int h  = tid >> 7;
            const int q  = (tid >> 2) & 31;
            const int kc = tid & 3;
            const int lq = qbase + q;
            const float4* qp = (const float4*)&sqkv[lq * 100 + h * 8];
            float4 q0 = qp[0], q1 = qp[1];
            const float scale = 0.35355339059327373f;

            float sc[16];
#pragma unroll
            for (int jj = 0; jj < 16; ++jj) {
                const int j = kc * 16 + ((jj + kc) & 15);
                const float4* kp = (const float4*)&sqkv[j * 100 + 32 + h * 8];
                sc[jj] = dot8(q0, q1, kp[0], kp[1]) * scale;
            }
            float m0 = fmaxf(fmaxf(fmaxf(sc[0], sc[1]),  fmaxf(sc[2], sc[3])),
                             fmaxf(fmaxf(sc[4], sc[5]),  fmaxf(sc[6], sc[7])));
            float m1 = fmaxf(fmaxf(fmaxf(sc[8], sc[9]),  fmaxf(sc[10], sc[11])),
                             fmaxf(fmaxf(sc[12], sc[13]), fmaxf(sc[14], sc[15])));
            float mx = fmaxf(m0, m1);
            mx = fmaxf(mx, __shfl_xor(mx, 1, 64));
            mx = fmaxf(mx, __shfl_xor(mx, 2, 64));

            float den = 0.f, a[8];
#pragma unroll
            for (int dd = 0; dd < 8; ++dd) a[dd] = 0.f;
#pragma unroll
            for (int jj = 0; jj < 16; ++jj) {
                const int j = kc * 16 + ((jj + kc) & 15);
                float wgt = __expf(sc[jj] - mx);
                den += wgt;
                const float4* vp = (const float4*)&sqkv[j * 100 + 64 + h * 8];
                float4 v0 = vp[0], v1 = vp[1];
                a[0] += wgt * v0.x;  a[1] += wgt * v0.y;
                a[2] += wgt * v0.z;  a[3] += wgt * v0.w;
                a[4] += wgt * v1.x;  a[5] += wgt * v1.y;
                a[6] += wgt * v1.z;  a[7] += wgt * v1.w;
            }
#pragma unroll
            for (int off = 1; off <= 2; off <<= 1) {
                den += __shfl_xor(den, off, 64);
#pragma unroll
                for (int dd = 0; dd < 8; ++dd) a[dd] += __shfl_xor(a[dd], off, 64);
            }
            float inv = 1.f / den;
            float r0, r1;
            if      (kc == 0) { r0 = a[0]; r1 = a[1]; }
            else if (kc == 1) { r0 = a[2]; r1 = a[3]; }
            else if (kc == 2) { r0 = a[4]; r1 = a[5]; }
            else              { r0 = a[6]; r1 = a[7]; }
            so[q * 36 + h * 8 + kc * 2 + 0] = r0 * inv;
            so[q * 36 + h * 8 + kc * 2 + 1] = r1 * inv;
        }
        __syncthreads();

        // FUSED out-proj + residual + LN + write (no LDS round-trip):
        // thread (r = tid>>4, cB = tid&15): row r's 16 threads are lanes
        // r*16..r*16+15 -> LN reduction fully in-wave (shfl_xor 1,2,4,8).
        {
            const int r  = tid >> 4;         // 0..31 local row
            const int cB = tid & 15;         // channels cB, cB+16
            const int lg = qbase + r;
            const float cvr = chip[b * 64 + lg];
            float orow[32];
            const float4* sop = (const float4*)&so[r * 36];
#pragma unroll
            for (int k4 = 0; k4 < 8; ++k4) {
                float4 t = sop[k4];
                orow[k4 * 4 + 0] = t.x;  orow[k4 * 4 + 1] = t.y;
                orow[k4 * 4 + 2] = t.z;  orow[k4 * 4 + 3] = t.w;
            }
            float res[2];
#pragma unroll
            for (int i = 0; i < 2; ++i) {
                int c = cB + i * 16;
                const float4* wr4 = (const float4*)&row_w[c * 32];
                float acc = row_b[c] + (cvr * ew[c] + eb[c] + pe[lg * 32 + c]);
#pragma unroll
                for (int k4 = 0; k4 < 8; ++k4) {
                    float4 wv = wr4[k4];
                    acc += orow[k4 * 4 + 0] * wv.x + orow[k4 * 4 + 1] * wv.y +
                           orow[k4 * 4 + 2] * wv.z + orow[k4 * 4 + 3] * wv.w;
                }
                res[i] = acc;
            }
            float s1 = res[0] + res[1];
#pragma unroll
            for (int off = 1; off <= 8; off <<= 1) s1 += __shfl_xor(s1, off, 64);
            float mu = s1 * (1.f / 32.f);
            float d0 = res[0] - mu, d1 = res[1] - mu;
            float s2 = d0 * d0 + d1 * d1;
#pragma unroll
            for (int off = 1; off <= 8; off <<= 1) s2 += __shfl_xor(s2, off, 64);
            float rstd = rsqrtf(s2 * (1.f / 32.f) + LN_EPS);
            msaR[(bs * 64 + lg) * 32 + cB]      = d0 * rstd * rlg[cB]      + rlb[cB];
            msaR[(bs * 64 + lg) * 32 + cB + 16] = d1 * rstd * rlg[cB + 16] + rlb[cB + 16];
        }
    }
    grid.sync();

    // ================= Phase 2: column attention =================
    {
        float* sx2   = smem;          // [32][33]
        float* sqkv2 = smem + 1056;   // [32*100]
        float* so2   = smem + 4256;   // [32][36]

        const int b2 = bx >> 3;
        const int l0 = (bx & 7) * 8;

        for (int n = tid; n < 1024; n += 512) {
            int r = n >> 5, c = n & 31;
            int lo = r >> 2, ss = r & 3;
            sx2[r * 33 + c] = msaR[((b2 * 4 + ss) * 64 + l0 + lo) * 32 + c];
        }
        __syncthreads();

        // qkv: 32 rows x 96 cols, 6 outputs/thread
        {
            const int rr  = tid & 31;
            const int cg2 = tid >> 5;
            float xr[32];
#pragma unroll
            for (int c = 0; c < 32; ++c) xr[c] = sx2[rr * 33 + c];
#pragma unroll
            for (int i = 0; i < 6; ++i) {
                int cc = i * 16 + cg2;
                const float4* wr4 = (const float4*)&ciw[cc * 32];
                float acc = cib[cc];
#pragma unroll
                for (int c4 = 0; c4 < 8; ++c4) {
                    float4 wv = wr4[c4];
                    acc += xr[c4 * 4 + 0] * wv.x + xr[c4 * 4 + 1] * wv.y +
                           xr[c4 * 4 + 2] * wv.z + xr[c4 * 4 + 3] * wv.w;
                }
                sqkv2[rr * 100 + cc] = acc;
            }
        }
        __syncthreads();

        // attention over 4 tracks: 128 units (lo, h, ia)
        if (tid < 128) {
            const int lo = tid >> 4, h = (tid >> 2) & 3, ia = tid & 3;
            const float scale = 0.35355339059327373f;
            const float4* qp = (const float4*)&sqkv2[(lo * 4 + ia) * 100 + h * 8];
            float4 q0 = qp[0], q1 = qp[1];
            float sc[4];
            float mx = -1e30f;
#pragma unroll
            for (int jj = 0; jj < 4; ++jj) {
                const float4* kp = (const float4*)&sqkv2[(lo * 4 + jj) * 100 + 32 + h * 8];
                sc[jj] = dot8(q0, q1, kp[0], kp[1]) * scale;
                mx = fmaxf(mx, sc[jj]);
            }
            float den = 0.f;
#pragma unroll
            for (int jj = 0; jj < 4; ++jj) { sc[jj] = __expf(sc[jj] - mx); den += sc[jj]; }
            float inv = 1.f / den;
            float a[8];
#pragma unroll
            for (int dd = 0; dd < 8; ++dd) a[dd] = 0.f;
#pragma unroll
            for (int jj = 0; jj < 4; ++jj) {
                const float4* vp = (const float4*)&sqkv2[(lo * 4 + jj) * 100 + 64 + h * 8];
                float4 v0 = vp[0], v1 = vp[1];
                float wgt = sc[jj];
                a[0] += wgt * v0.x;  a[1] += wgt * v0.y;
                a[2] += wgt * v0.z;  a[3] += wgt * v0.w;
                a[4] += wgt * v1.x;  a[5] += wgt * v1.y;
                a[6] += wgt * v1.z;  a[7] += wgt * v1.w;
            }
#pragma unroll
            for (int dd = 0; dd < 8; ++dd) so2[(lo * 4 + ia) * 36 + h * 8 + dd] = a[dd] * inv;
        }
        __syncthreads();

        // FUSED out-proj + residual + LN -> sqkv2 (dead after attn; no WAR
        // hazard with so2 reads). Same 16-lane in-wave reduction layout.
        {
            const int r  = tid >> 4;         // 0..31
            const int cB = tid & 15;
            float orow[32];
            const float4* sop = (const float4*)&so2[r * 36];
#pragma unroll
            for (int k4 = 0; k4 < 8; ++k4) {
                float4 t = sop[k4];
                orow[k4 * 4 + 0] = t.x;  orow[k4 * 4 + 1] = t.y;
                orow[k4 * 4 + 2] = t.z;  orow[k4 * 4 + 3] = t.w;
            }
            float res[2];
#pragma unroll
            for (int i = 0; i < 2; ++i) {
                int c = cB + i * 16;
                const float4* wr4 = (const float4*)&cow[c * 32];
                float acc = cob[c] + sx2[r * 33 + c];
#pragma unroll
                for (int k4 = 0; k4 < 8; ++k4) {
                    float4 wv = wr4[k4];
                    acc += orow[k4 * 4 + 0] * wv.x + orow[k4 * 4 + 1] * wv.y +
                           orow[k4 * 4 + 2] * wv.z + orow[k4 * 4 + 3] * wv.w;
                }
                res[i] = acc;
            }
            float s1 = res[0] + res[1];
#pragma unroll
            for (int off = 1; off <= 8; off <<= 1) s1 += __shfl_xor(s1, off, 64);
            float mu = s1 * (1.f / 32.f);
            float d0 = res[0] - mu, d1 = res[1] - mu;
            float s2 = d0 * d0 + d1 * d1;
#pragma unroll
            for (int off = 1; off <= 8; off <<= 1) s2 += __shfl_xor(s2, off, 64);
            float rstd = rsqrtf(s2 * (1.f / 32.f) + LN_EPS);
            sqkv2[r * 100 + cB]      = d0 * rstd;    // pre-gamma normalized
            sqkv2[r * 100 + cB + 16] = d1 * rstd;
        }
        __syncthreads();

        // track mean (gamma/beta folded) + row norm via shuffle: 8 lo x 32 c
        if (tid < 256) {
            const int lo = tid >> 5, c = tid & 31;
            float mval = 0.25f * (sqkv2[(lo * 4 + 0) * 100 + c] +
                                  sqkv2[(lo * 4 + 1) * 100 + c] +
                                  sqkv2[(lo * 4 + 2) * 100 + c] +
                                  sqkv2[(lo * 4 + 3) * 100 + c]) * clg[c] + clb[c];
            mbuf[(b2 * 64 + l0 + lo) * 32 + c] = mval;
            float q2 = mval * mval;
#pragma unroll
            for (int off = 16; off >= 1; off >>= 1) q2 += __shfl_xor(q2, off, 64);
            if (c == 0) nbuf[b2 * 64 + l0 + lo] = sqrtf(q2);
        }
    }
}

// ---------------------------------------------------------------------------
// Fallback (non-coop) path: R8's proven 4-kernel pipeline.
// ---------------------------------------------------------------------------
__global__ __launch_bounds__(256, 4) void k_qkv1(
    const float* __restrict__ ctcf, const float* __restrict__ hac,
    const float* __restrict__ me1,  const float* __restrict__ me3,
    const float* __restrict__ ew,   const float* __restrict__ eb,
    const float* __restrict__ pe,
    const float* __restrict__ riw,  const float* __restrict__ rib,
    float* __restrict__ qkvR)
{
    const int bx   = blockIdx.x;
    const int slab = bx >> 8;
    const int bs   = bx & 255;
    const int s    = bs & 3, b = bs >> 2;
    const int tid  = threadIdx.x;
    const int r    = tid >> 2;
    const int cc0  = slab * 16 + (tid & 3) * 4;

    const float* chip = (s == 0) ? ctcf : (s == 1) ? hac : (s == 2) ? me1 : me3;
    const float cv = chip[b * 64 + r];

    const float4* ew4 = (const float4*)ew;
    const float4* eb4 = (const float4*)eb;
    const float4* pe4 = (const float4*)&pe[r * 32];
    const float4* w0  = (const float4*)&riw[(cc0 + 0) * 32];
    const float4* w1  = (const float4*)&riw[(cc0 + 1) * 32];
    const float4* w2  = (const float4*)&riw[(cc0 + 2) * 32];
    const float4* w3  = (const float4*)&riw[(cc0 + 3) * 32];

    float a0 = rib[cc0 + 0], a1 = rib[cc0 + 1], a2 = rib[cc0 + 2], a3 = rib[cc0 + 3];
#pragma unroll
    for (int c4 = 0; c4 < 8; ++c4) {
        float4 e = ew4[c4], bb = eb4[c4], pv = pe4[c4];
        float x0 = cv * e.x + bb.x + pv.x;
        float x1 = cv * e.y + bb.y + pv.y;
        float x2 = cv * e.z + bb.z + pv.z;
        float x3 = cv * e.w + bb.w + pv.w;
        float4 v0 = w0[c4], v1 = w1[c4], v2 = w2[c4], v3 = w3[c4];
        a0 += x0 * v0.x + x1 * v0.y + x2 * v0.z + x3 * v0.w;
        a1 += x0 * v1.x + x1 * v1.y + x2 * v1.z + x3 * v1.w;
        a2 += x0 * v2.x + x1 * v2.y + x2 * v2.z + x3 * v2.w;
        a3 += x0 * v3.x + x1 * v3.y + x2 * v3.z + x3 * v3.w;
    }
    *(float4*)&qkvR[bs * 6144 + r * 96 + cc0] = make_float4(a0, a1, a2, a3);
}

__global__ __launch_bounds__(256, 4) void k_attn1(
    const float* __restrict__ ctcf, const float* __restrict__ hac,
    const float* __restrict__ me1,  const float* __restrict__ me3,
    const float* __restrict__ ew,   const float* __restrict__ eb,
    const float* __restrict__ pe,
    const float* __restrict__ qkvR,
    const float* __restrict__ row_w,const float* __restrict__ row_b,
    const float* __restrict__ rlg,  const float* __restrict__ rlb,
    float* __restrict__ msaR)
{
    __shared__ float kv[64][68];
    __shared__ float so[16][36];

    const int bx = blockIdx.x;
    const int bs = bx >> 2;
    const int q0 = (bx & 3) * 16;
    const int s  = bs & 3, b = bs >> 2;
    const int tid = threadIdx.x;

    {
        const float* src = qkvR + bs * 6144;
#pragma unroll
        for (int k = 0; k < 4; ++k) {
            int idx  = tid + k * 256;
            int row  = idx >> 4;
            int part = idx & 15;
            *(float4*)&kv[row][part * 4] =
                *(const float4*)&src[row * 96 + 32 + part * 4];
        }
    }
    __syncthreads();

    {
        const int h   = tid >> 6;
        const int q16 = (tid >> 2) & 15;
        const int kc  = tid & 3;
        const int lq  = q0 + q16;
        const float4* qp = (const float4*)&qkvR[bs * 6144 + lq * 96 + h * 8];
        float4 qv0 = qp[0], qv1 = qp[1];
        const float scale = 0.35355339059327373f;

        float sc[16];
#pragma unroll
        for (int jj = 0; jj < 16; ++jj) {
            const int j = kc * 16 + ((jj + kc) & 15);
            const float4* kp = (const float4*)&kv[j][h * 8];
            sc[jj] = dot8(qv0, qv1, kp[0], kp[1]) * scale;
        }
        float m0 = fmaxf(fmaxf(fmaxf(sc[0], sc[1]),  fmaxf(sc[2], sc[3])),
                         fmaxf(fmaxf(sc[4], sc[5]),  fmaxf(sc[6], sc[7])));
        float m1 = fmaxf(fmaxf(fmaxf(sc[8], sc[9]),  fmaxf(sc[10], sc[11])),
                         fmaxf(fmaxf(sc[12], sc[13]), fmaxf(sc[14], sc[15])));
        float mx = fmaxf(m0, m1);
        mx = fmaxf(mx, __shfl_xor(mx, 1, 64));
        mx = fmaxf(mx, __shfl_xor(mx, 2, 64));

        float den = 0.f, a[8];
#pragma unroll
        for (int dd = 0; dd < 8; ++dd) a[dd] = 0.f;
#pragma unroll
        for (int jj = 0; jj < 16; ++jj) {
            const int j = kc * 16 + ((jj + kc) & 15);
            float wgt = __expf(sc[jj] - mx);
            den += wgt;
            const float4* vp = (const float4*)&kv[j][32 + h * 8];
            float4 v0 = vp[0], v1 = vp[1];
            a[0] += wgt * v0.x;  a[1] += wgt * v0.y;
            a[2] += wgt * v0.z;  a[3] += wgt * v0.w;
            a[4] += wgt * v1.x;  a[5] += wgt * v1.y;
            a[6] += wgt * v1.z;  a[7] += wgt * v1.w;
        }
#pragma unroll
        for (int off = 1; off <= 2; off <<= 1) {
            den += __shfl_xor(den, off, 64);
#pragma unroll
            for (int dd = 0; dd < 8; ++dd) a[dd] += __shfl_xor(a[dd], off, 64);
        }
        float inv = 1.f / den;
        float r0, r1;
        if      (kc == 0) { r0 = a[0]; r1 = a[1]; }
        else if (kc == 1) { r0 = a[2]; r1 = a[3]; }
        else if (kc == 2) { r0 = a[4]; r1 = a[5]; }
        else              { r0 = a[6]; r1 = a[7]; }
        so[q16][h * 8 + kc * 2 + 0] = r0 * inv;
        so[q16][h * 8 + kc * 2 + 1] = r1 * inv;
    }
    __syncthreads();

    {
        const int c = tid & 31;
        const float* chip = (s == 0) ? ctcf : (s == 1) ? hac : (s == 2) ? me1 : me3;
#pragma unroll
        for (int p = 0; p < 2; ++p) {
            const int r  = p * 8 + (tid >> 5);
            const int lq = q0 + r;
            const float cv = chip[b * 64 + lq];

            const float4* sop = (const float4*)&so[r][0];
            const float4* wr4 = (const float4*)&row_w[c * 32];
            float acc = row_b[c] + (cv * ew[c] + eb[c] + pe[lq * 32 + c]);
#pragma unroll
            for (int k4 = 0; k4 < 8; ++k4) {
                float4 ov = sop[k4], wv = wr4[k4];
                acc += ov.x * wv.x + ov.y * wv.y + ov.z * wv.z + ov.w * wv.w;
            }
            float s1 = acc;
#pragma unroll
            for (int off = 16; off >= 1; off >>= 1) s1 += __shfl_xor(s1, off, 64);
            float mu = s1 * (1.f / 32.f);
            float d = acc - mu;
            float s2 = d * d;
#pragma unroll
            for (int off = 16; off >= 1; off >>= 1) s2 += __shfl_xor(s2, off, 64);
            float rstd = rsqrtf(s2 * (1.f / 32.f) + LN_EPS);
            msaR[(bs * 64 + lq) * 32 + c] = d * rstd * rlg[c] + rlb[c];
        }
    }
}

__global__ __launch_bounds__(256, 4) void k_colfused(
    const float* __restrict__ msaR,
    const float* __restrict__ ciw,  const float* __restrict__ cib,
    const float* __restrict__ cow,  const float* __restrict__ cob,
    const float* __restrict__ clg,  const float* __restrict__ clb,
    float* __restrict__ m_out, float* __restrict__ nrm_out)
{
    __shared__ float sx[8][36];
    __shared__ float sq[8][100];
    __shared__ float so[8][36];
    __shared__ float pr[8][36];

    const int bx = blockIdx.x;
    const int b  = bx >> 5;
    const int l0 = (bx & 31) * 2;
    const int tid = threadIdx.x;
    const int r  = tid >> 5;
    const int c  = tid & 31;

    {
        int lo = r >> 2, s = r & 3;
        sx[r][c] = msaR[((b * 4 + s) * 64 + l0 + lo) * 32 + c];
    }
    __syncthreads();

    {
        const float4* xr4 = (const float4*)&sx[r][0];
        const float4* wq  = (const float4*)&ciw[c * 32];
        const float4* wk  = (const float4*)&ciw[(32 + c) * 32];
        const float4* wv  = (const float4*)&ciw[(64 + c) * 32];
        float aq = cib[c], ak = cib[32 + c], av = cib[64 + c];
#pragma unroll
        for (int k4 = 0; k4 < 8; ++k4) {
            float4 xv = xr4[k4];
            float4 q = wq[k4], k = wk[k4], v = wv[k4];
            aq += xv.x * q.x + xv.y * q.y + xv.z * q.z + xv.w * q.w;
            ak += xv.x * k.x + xv.y * k.y + xv.z * k.z + xv.w * k.w;
            av += xv.x * v.x + xv.y * v.y + xv.z * v.z + xv.w * v.w;
        }
        sq[r][c] = aq; sq[r][32 + c] = ak; sq[r][64 + c] = av;
    }
    __syncthreads();

    if (tid < 32) {
        const int lo = tid >> 4, ia = (tid >> 2) & 3, h = tid & 3;
        const float scale = 0.35355339059327373f;
        const float4* qp = (const float4*)&sq[lo * 4 + ia][h * 8];
        float4 q0 = qp[0], q1 = qp[1];
        float sc[4];
        float mx = -1e30f;
#pragma unroll
        for (int jj = 0; jj < 4; ++jj) {
            const float4* kp = (const float4*)&sq[lo * 4 + jj][32 + h * 8];
            sc[jj] = dot8(q0, q1, kp[0], kp[1]) * scale;
            mx = fmaxf(mx, sc[jj]);
        }
        float den = 0.f;
#pragma unroll
        for (int jj = 0; jj < 4; ++jj) { sc[jj] = __expf(sc[jj] - mx); den += sc[jj]; }
        float inv = 1.f / den;
        float a[8];
#pragma unroll
        for (int dd = 0; dd < 8; ++dd) a[dd] = 0.f;
#pragma unroll
        for (int jj = 0; jj < 4; ++jj) {
            const float4* vp = (const float4*)&sq[lo * 4 + jj][64 + h * 8];
            float4 v0 = vp[0], v1 = vp[1];
            float wgt = sc[jj];
            a[0] += wgt * v0.x;  a[1] += wgt * v0.y;
            a[2] += wgt * v0.z;  a[3] += wgt * v0.w;
            a[4] += wgt * v1.x;  a[5] += wgt * v1.y;
            a[6] += wgt * v1.z;  a[7] += wgt * v1.w;
        }
#pragma unroll
        for (int dd = 0; dd < 8; ++dd) so[lo * 4 + ia][h * 8 + dd] = a[dd] * inv;
    }
    __syncthreads();

    {
        const float4* sop = (const float4*)&so[r][0];
        const float4* wr4 = (const float4*)&cow[c * 32];
        float acc = cob[c] + sx[r][c];
#pragma unroll
        for (int k4 = 0; k4 < 8; ++k4) {
            float4 ov = sop[k4], wv = wr4[k4];
            acc += ov.x * wv.x + ov.y * wv.y + ov.z * wv.z + ov.w * wv.w;
        }
        float s1 = acc;
#pragma unroll
        for (int off = 16; off >= 1; off >>= 1) s1 += __shfl_xor(s1, off, 64);
        float mu = s1 * (1.f / 32.f);
        float d = acc - mu;
        float s2 = d * d;
#pragma unroll
        for (int off = 16; off >= 1; off >>= 1) s2 += __shfl_xor(s2, off, 64);
        float rstd = rsqrtf(s2 * (1.f / 32.f) + LN_EPS);
        pr[r][c] = d * rstd;
    }
    __syncthreads();

    if (tid < 64) {
        const int lo = tid >> 5, cc = tid & 31;
        float mval = 0.25f * (pr[lo * 4 + 0][cc] + pr[lo * 4 + 1][cc] +
                              pr[lo * 4 + 2][cc] + pr[lo * 4 + 3][cc]) *
                     clg[cc] + clb[cc];
        m_out[(b * 64 + l0 + lo) * 32 + cc] = mval;
        float q2 = mval * mval;
#pragma unroll
        for (int off = 16; off >= 1; off >>= 1) q2 += __shfl_xor(q2, off, 64);
        if (cc == 0) nrm_out[b * 64 + l0 + lo] = sqrtf(q2);
    }
}

// ---------------------------------------------------------------------------
// Kernel 3: pair features (measured 19.6 us). 1024 x 256, (256,4).
// ---------------------------------------------------------------------------
__global__ __launch_bounds__(256, 4) void k_pair(
    const float* __restrict__ m, const float* __restrict__ nrm,
    const float* __restrict__ pw, const float* __restrict__ pb,
    const float* __restrict__ pg, const float* __restrict__ pbeta,
    float* __restrict__ out)
{
    __shared__ float smj[64][36];
    __shared__ float sT[4 * 520];
    __shared__ float snj[64];
    __shared__ float sbias[16], sgam[16], sbet[16];

    const int bx = blockIdx.x;
    const int b  = bx >> 4;
    const int i0 = (bx & 15) * 4;
    const int tid = threadIdx.x;
    const int lane = tid & 63, w = tid >> 6;

    const int rem0 = tid, rem1 = tid + 256;
    const float* pw0 = pw + (rem0 >> 5) * 1024 + (rem0 & 31);
    const float* pw1 = pw + (rem1 >> 5) * 1024 + (rem1 & 31);
    float w0[32], w1[32];
#pragma unroll
    for (int c = 0; c < 32; ++c) { w0[c] = pw0[c * 32]; w1[c] = pw1[c * 32]; }

    const float* mb = m + b * 2048;
    for (int n = tid; n < 2048; n += 256) smj[n >> 5][n & 31] = mb[n];
    if (tid < 64) snj[tid] = nrm[b * 64 + tid];
    if (tid < 16) {
        sbias[tid] = pb[tid];
        sgam[tid]  = pg[tid];
        sbet[tid]  = pbeta[tid];
    }
    __syncthreads();

#pragma unroll
    for (int il = 0; il < 4; ++il) {
        const float4* mr4 = (const float4*)&smj[i0 + il][0];
        float a0 = 0.f, a1 = 0.f;
#pragma unroll
        for (int c4 = 0; c4 < 8; ++c4) {
            float4 mv = mr4[c4];
            a0 += mv.x * w0[c4 * 4 + 0] + mv.y * w0[c4 * 4 + 1] +
                  mv.z * w0[c4 * 4 + 2] + mv.w * w0[c4 * 4 + 3];
            a1 += mv.x * w1[c4 * 4 + 0] + mv.y * w1[c4 * 4 + 1] +
                  mv.z * w1[c4 * 4 + 2] + mv.w * w1[c4 * 4 + 3];
        }
        sT[il * 520 + rem0] = a0;
        sT[il * 520 + rem1] = a1;
    }
    __syncthreads();

    const int j = lane;
    float mj[32];
    {
        const float4* mjp = (const float4*)&smj[j][0];
#pragma unroll
        for (int d4 = 0; d4 < 8; ++d4) {
            float4 t = mjp[d4];
            mj[d4 * 4 + 0] = t.x;  mj[d4 * 4 + 1] = t.y;
            mj[d4 * 4 + 2] = t.z;  mj[d4 * 4 + 3] = t.w;
        }
    }
    const float nj = snj[j];

    {
        const int il = w;
        const int ig = i0 + il;
        const float invn = 1.f / fmaxf(snj[ig] * nj, 1e-6f);
        float f[16];
#pragma unroll
        for (int cp = 0; cp < 16; ++cp) {
            const float4* tr = (const float4*)&sT[il * 520 + cp * 32];
            float acc = 0.f;
#pragma unroll
            for (int d4 = 0; d4 < 8; ++d4) {
                float4 tv = tr[d4];
                acc += tv.x * mj[d4 * 4 + 0] + tv.y * mj[d4 * 4 + 1] +
                       tv.z * mj[d4 * 4 + 2] + tv.w * mj[d4 * 4 + 3];
            }
            f[cp] = acc * invn + sbias[cp];
        }
        float mu = 0.f;
#pragma unroll
        for (int cp = 0; cp < 16; ++cp) mu += f[cp];
        mu *= (1.f / 16.f);
        float var = 0.f;
#pragma unroll
        for (int cp = 0; cp < 16; ++cp) { float d = f[cp] - mu; var += d * d; }
        var *= (1.f / 16.f);
        const float rstd = rsqrtf(var + LN_EPS);
#pragma unroll
        for (int cp = 0; cp < 16; ++cp) {
            float v = (f[cp] - mu) * rstd * sgam[cp] + sbet[cp];
            float sl = v / (1.f + __expf(-v));
            out[((b * 16 + cp) * 64 + ig) * 64 + j] = sl;
        }
    }
}

// ---------------------------------------------------------------------------
extern "C" void kernel_launch(void* const* d_in, const int* in_sizes, int n_in,
                              void* d_out, int out_size, void* d_ws, size_t ws_size,
                              hipStream_t stream) {
    const float* ctcf  = (const float*)d_in[0];
    const float* hac   = (const float*)d_in[1];
    const float* me1   = (const float*)d_in[2];
    const float* me3   = (const float*)d_in[3];
    const float* ew    = (const float*)d_in[4];
    const float* ebias = (const float*)d_in[5];
    const float* pe    = (const float*)d_in[6];
    const float* riw   = (const float*)d_in[7];
    const float* rib   = (const float*)d_in[8];
    const float* row_  = (const float*)d_in[9];
    const float* rob   = (const float*)d_in[10];
    const float* rlg   = (const float*)d_in[11];
    const float* rlb   = (const float*)d_in[12];
    const float* ciw   = (const float*)d_in[13];
    const float* cib   = (const float*)d_in[14];
    const float* cow   = (const float*)d_in[15];
    const float* cob   = (const float*)d_in[16];
    const float* clg   = (const float*)d_in[17];
    const float* clb   = (const float*)d_in[18];
    const float* pw    = (const float*)d_in[19];
    const float* pb    = (const float*)d_in[20];
    const float* pg    = (const float*)d_in[21];
    const float* pbt   = (const float*)d_in[22];

    float* outp = (float*)d_out;

    // d_out scratch while final out unwritten:
    //   msaR @ 0      : 524288 floats (consumed by phase 2 / k_colfused)
    //   qkvR @ 524288 : 1572864 floats (fallback path only)
    float* msaR = (float*)d_out;
    float* qkvR = msaR + 524288;
    float* mbuf = (float*)d_ws;                  // 64*64*32 floats
    float* nbuf = mbuf + 64 * 64 * 32;           // 64*64 floats

    static int s_coop = -1;
    if (s_coop < 0) {
        int nb = 0;
        hipError_t e = hipOccupancyMaxActiveBlocksPerMultiprocessor(
            &nb, k12, 512, 0);
        s_coop = (e == hipSuccess && nb >= 2) ? 1 : 0;
    }

    bool done12 = false;
    if (s_coop) {
        void* args[] = {
            (void*)&ctcf, (void*)&hac, (void*)&me1, (void*)&me3,
            (void*)&ew,   (void*)&ebias, (void*)&pe,
            (void*)&riw,  (void*)&rib, (void*)&row_, (void*)&rob,
            (void*)&rlg,  (void*)&rlb,
            (void*)&ciw,  (void*)&cib, (void*)&cow, (void*)&cob,
            (void*)&clg,  (void*)&clb,
            (void*)&msaR, (void*)&mbuf, (void*)&nbuf
        };
        hipError_t le = hipLaunchCooperativeKernel((void*)k12, dim3(512),
                                                   dim3(512), args, 0, stream);
        if (le == hipSuccess) done12 = true; else s_coop = 0;
    }
    if (!done12) {
        k_qkv1<<<1536, 256, 0, stream>>>(ctcf, hac, me1, me3, ew, ebias, pe,
                                         riw, rib, qkvR);
        k_attn1<<<1024, 256, 0, stream>>>(ctcf, hac, me1, me3, ew, ebias, pe,
                                          qkvR, row_, rob, rlg, rlb, msaR);
        k_colfused<<<2048, 256, 0, stream>>>(msaR, ciw, cib, cow, cob, clg, clb,
                                             mbuf, nbuf);
    }
    k_pair<<<1024, 256, 0, stream>>>(mbuf, nbuf, pw, pb, pg, pbt, outp);
}

// Round 11
// 143.563 us; speedup vs baseline: 1.3342x; 1.3342x over previous
//
#include <hip/hip_runtime.h>

#define LN_EPS 1e-5f

__device__ __forceinline__ float dot8(float4 a0, float4 a1, float4 b0, float4 b1) {
    return a0.x * b0.x + a0.y * b0.y + a0.z * b0.z + a0.w * b0.w +
           a1.x * b1.x + a1.y * b1.y + a1.z * b1.z + a1.w * b1.w;
}

// ---------------------------------------------------------------------------
// NOTE (R10 finding): hipLaunchCooperativeKernel fails under hipGraph capture
// (the harness's timed path), so every "coop" round actually timed the
// fallback. R8-R10 timed the slow 4-kernel fallback (191.5 us); the best
// timed configuration is the R6 fallback trio (142.7 us). This round launches
// that trio DIRECTLY (no coop), so timed path == profiled path and next
// round's rocprof decomposes the real kernels.
// ---------------------------------------------------------------------------

// ---------------------------------------------------------------------------
// Kernel 1: embed + row attention (64 bins) + residual + LN -> msaR.
// 512 blocks (b,s,query-half) x 512 threads, (512,4). Embed fused into
// registers; QKV as 12-col contiguous chunk per wave (3 ds_write_b128);
// two-pass softmax with 4-way kc split + shuffle merge; residual recomputed.
// Timed at ~142.7 total as part of the R6 trio.
// ---------------------------------------------------------------------------
__global__ __launch_bounds__(512, 4) void k_row(
    const float* __restrict__ ctcf, const float* __restrict__ hac,
    const float* __restrict__ me1,  const float* __restrict__ me3,
    const float* __restrict__ ew,   const float* __restrict__ eb,
    const float* __restrict__ pe,
    const float* __restrict__ w_in, const float* __restrict__ b_in,
    const float* __restrict__ w_out,const float* __restrict__ b_out,
    const float* __restrict__ ln_g, const float* __restrict__ ln_b,
    float* __restrict__ msaR)
{
    __shared__ float sqkv[64 * 100];
    __shared__ float so[32][36];

    const int blk = blockIdx.x;
    const int qh  = blk & 1;
    const int s   = (blk >> 1) & 3;
    const int b   = blk >> 3;
    const int qbase = qh * 32;
    const int tid = threadIdx.x;

    const float* chip = (s == 0) ? ctcf : (s == 1) ? hac : (s == 2) ? me1 : me3;

    const int l  = tid & 63;
    const int cg = __builtin_amdgcn_readfirstlane(tid >> 6);

    // fused embed into registers
    float xr[32];
    {
        const float cv = chip[b * 64 + l];
        const float4* pe4 = (const float4*)&pe[l * 32];
        const float4* ew4 = (const float4*)ew;
        const float4* eb4 = (const float4*)eb;
#pragma unroll
        for (int c4 = 0; c4 < 8; ++c4) {
            float4 pv = pe4[c4], e = ew4[c4], bb = eb4[c4];
            xr[c4 * 4 + 0] = cv * e.x + bb.x + pv.x;
            xr[c4 * 4 + 1] = cv * e.y + bb.y + pv.y;
            xr[c4 * 4 + 2] = cv * e.z + bb.z + pv.z;
            xr[c4 * 4 + 3] = cv * e.w + bb.w + pv.w;
        }
    }

    // QKV: contiguous 12-col chunk per wave -> 3 ds_write_b128
    {
        const int cc0 = cg * 12;
        float acc[12];
#pragma unroll
        for (int ii = 0; ii < 12; ++ii) acc[ii] = b_in[cc0 + ii];
#pragma unroll
        for (int ii = 0; ii < 12; ++ii) {
            const float4* wr4 = (const float4*)&w_in[(cc0 + ii) * 32];
#pragma unroll
            for (int c4 = 0; c4 < 8; ++c4) {
                float4 wv = wr4[c4];
                acc[ii] += xr[c4 * 4 + 0] * wv.x + xr[c4 * 4 + 1] * wv.y +
                           xr[c4 * 4 + 2] * wv.z + xr[c4 * 4 + 3] * wv.w;
            }
        }
        float* dst = &sqkv[l * 100 + cc0];
        *(float4*)(dst + 0) = make_float4(acc[0], acc[1], acc[2],  acc[3]);
        *(float4*)(dst + 4) = make_float4(acc[4], acc[5], acc[6],  acc[7]);
        *(float4*)(dst + 8) = make_float4(acc[8], acc[9], acc[10], acc[11]);
    }
    __syncthreads();

    // attention, two-pass: thread (h = tid>>7, q = (tid>>2)&31, kc = tid&3)
    {
        const int h  = tid >> 7;
        const int q  = (tid >> 2) & 31;
        const int kc = tid & 3;
        const int lq = qbase + q;
        const float4* qp = (const float4*)&sqkv[lq * 100 + h * 8];
        float4 q0 = qp[0], q1 = qp[1];
        const float scale = 0.35355339059327373f;  // 1/sqrt(8)

        float sc[16];
#pragma unroll
        for (int jj = 0; jj < 16; ++jj) {
            const int j = kc * 16 + ((jj + kc) & 15);   // bank-staggered
            const float4* kp = (const float4*)&sqkv[j * 100 + 32 + h * 8];
            sc[jj] = dot8(q0, q1, kp[0], kp[1]) * scale;
        }
        float m0 = fmaxf(fmaxf(fmaxf(sc[0], sc[1]),  fmaxf(sc[2], sc[3])),
                         fmaxf(fmaxf(sc[4], sc[5]),  fmaxf(sc[6], sc[7])));
        float m1 = fmaxf(fmaxf(fmaxf(sc[8], sc[9]),  fmaxf(sc[10], sc[11])),
                         fmaxf(fmaxf(sc[12], sc[13]), fmaxf(sc[14], sc[15])));
        float mx = fmaxf(m0, m1);
        mx = fmaxf(mx, __shfl_xor(mx, 1, 64));
        mx = fmaxf(mx, __shfl_xor(mx, 2, 64));

        float den = 0.f, a[8];
#pragma unroll
        for (int dd = 0; dd < 8; ++dd) a[dd] = 0.f;
#pragma unroll
        for (int jj = 0; jj < 16; ++jj) {
            const int j = kc * 16 + ((jj + kc) & 15);
            float w = __expf(sc[jj] - mx);
            den += w;
            const float4* vp = (const float4*)&sqkv[j * 100 + 64 + h * 8];
            float4 v0 = vp[0], v1 = vp[1];
            a[0] += w * v0.x;  a[1] += w * v0.y;
            a[2] += w * v0.z;  a[3] += w * v0.w;
            a[4] += w * v1.x;  a[5] += w * v1.y;
            a[6] += w * v1.z;  a[7] += w * v1.w;
        }
#pragma unroll
        for (int off = 1; off <= 2; off <<= 1) {
            den += __shfl_xor(den, off, 64);
#pragma unroll
            for (int dd = 0; dd < 8; ++dd) a[dd] += __shfl_xor(a[dd], off, 64);
        }
        float inv = 1.f / den;
        float r0, r1;
        if      (kc == 0) { r0 = a[0]; r1 = a[1]; }
        else if (kc == 1) { r0 = a[2]; r1 = a[3]; }
        else if (kc == 2) { r0 = a[4]; r1 = a[5]; }
        else              { r0 = a[6]; r1 = a[7]; }
        so[q][h * 8 + kc * 2 + 0] = r0 * inv;
        so[q][h * 8 + kc * 2 + 1] = r1 * inv;
    }
    __syncthreads();

    // out proj + residual (recomputed) -> sqkv rows 0..31
    {
        const int lq2 = tid & 31;
        const int cB  = tid >> 5;
        const int lg  = qbase + lq2;
        const float cvr = chip[b * 64 + lg];
        float orow[32];
        const float4* sop = (const float4*)&so[lq2][0];
#pragma unroll
        for (int k4 = 0; k4 < 8; ++k4) {
            float4 t = sop[k4];
            orow[k4 * 4 + 0] = t.x;  orow[k4 * 4 + 1] = t.y;
            orow[k4 * 4 + 2] = t.z;  orow[k4 * 4 + 3] = t.w;
        }
#pragma unroll
        for (int i = 0; i < 2; ++i) {
            int c = cB + i * 16;
            const float4* wr4 = (const float4*)&w_out[c * 32];
            float acc = b_out[c] + (cvr * ew[c] + eb[c] + pe[lg * 32 + c]);
#pragma unroll
            for (int k4 = 0; k4 < 8; ++k4) {
                float4 wv = wr4[k4];
                acc += orow[k4 * 4 + 0] * wv.x + orow[k4 * 4 + 1] * wv.y +
                       orow[k4 * 4 + 2] * wv.z + orow[k4 * 4 + 3] * wv.w;
            }
            sqkv[lq2 * 100 + c] = acc;
        }
    }
    __syncthreads();

    // LN + write via 32-lane shuffle reductions
    {
        const int c = tid & 31;
#pragma unroll
        for (int p = 0; p < 2; ++p) {
            int r = p * 16 + (tid >> 5);
            float v = sqkv[r * 100 + c];
            float s1 = v;
#pragma unroll
            for (int off = 16; off >= 1; off >>= 1) s1 += __shfl_xor(s1, off, 64);
            float mu = s1 * (1.f / 32.f);
            float d = v - mu;
            float s2 = d * d;
#pragma unroll
            for (int off = 16; off >= 1; off >>= 1) s2 += __shfl_xor(s2, off, 64);
            float rstd = rsqrtf(s2 * (1.f / 32.f) + LN_EPS);
            msaR[((b * 4 + s) * 64 + qbase + r) * 32 + c] = d * rstd * ln_g[c] + ln_b[c];
        }
    }
}

// ---------------------------------------------------------------------------
// Kernel 2: column attention (4 tracks) + residual + LN + track mean + norm.
// 1024 blocks (b, 4-bin chunk) x 256 threads, (256,4). 4 blocks/CU.
// ---------------------------------------------------------------------------
__global__ __launch_bounds__(256, 4) void k_col(
    const float* __restrict__ msaR,
    const float* __restrict__ w_in, const float* __restrict__ b_in,
    const float* __restrict__ w_out,const float* __restrict__ b_out,
    const float* __restrict__ ln_g, const float* __restrict__ ln_b,
    float* __restrict__ m_out, float* __restrict__ nrm_out)
{
    __shared__ float sx[16][33];
    __shared__ float sqkv[16 * 100];
    __shared__ float so[16][33];

    const int bx = blockIdx.x;
    const int b  = bx >> 4;
    const int l0 = (bx & 15) * 4;
    const int tid = threadIdx.x;

    for (int n = tid; n < 512; n += 256) {
        int r = n >> 5, c = n & 31;
        int lo = r >> 2, s = r & 3;
        sx[r][c] = msaR[((b * 4 + s) * 64 + l0 + lo) * 32 + c];
    }
    __syncthreads();

    // qkv: 16 rows x 96 cols, 6 outputs/thread
    {
        const int rr = tid & 15;
        const int cg = tid >> 4;
        float xr[32];
#pragma unroll
        for (int c = 0; c < 32; ++c) xr[c] = sx[rr][c];
#pragma unroll
        for (int i = 0; i < 6; ++i) {
            int cc = i * 16 + cg;
            const float4* wr4 = (const float4*)&w_in[cc * 32];
            float acc = b_in[cc];
#pragma unroll
            for (int c4 = 0; c4 < 8; ++c4) {
                float4 wv = wr4[c4];
                acc += xr[c4 * 4 + 0] * wv.x + xr[c4 * 4 + 1] * wv.y +
                       xr[c4 * 4 + 2] * wv.z + xr[c4 * 4 + 3] * wv.w;
            }
            sqkv[rr * 100 + cc] = acc;
        }
    }
    __syncthreads();

    // attention over 4 tracks: 64 units (lo, h, ia)
    if (tid < 64) {
        const int lo = tid >> 4, h = (tid >> 2) & 3, ia = tid & 3;
        const float scale = 0.35355339059327373f;
        const float4* qp = (const float4*)&sqkv[(lo * 4 + ia) * 100 + h * 8];
        float4 q0 = qp[0], q1 = qp[1];
        float sc[4];
        float mx = -1e30f;
#pragma unroll
        for (int jj = 0; jj < 4; ++jj) {
            const float4* kp = (const float4*)&sqkv[(lo * 4 + jj) * 100 + 32 + h * 8];
            sc[jj] = dot8(q0, q1, kp[0], kp[1]) * scale;
            mx = fmaxf(mx, sc[jj]);
        }
        float den = 0.f;
#pragma unroll
        for (int jj = 0; jj < 4; ++jj) { sc[jj] = __expf(sc[jj] - mx); den += sc[jj]; }
        float inv = 1.f / den;
        float a[8];
#pragma unroll
        for (int dd = 0; dd < 8; ++dd) a[dd] = 0.f;
#pragma unroll
        for (int jj = 0; jj < 4; ++jj) {
            const float4* vp = (const float4*)&sqkv[(lo * 4 + jj) * 100 + 64 + h * 8];
            float4 v0 = vp[0], v1 = vp[1];
            float wgt = sc[jj];
            a[0] += wgt * v0.x;  a[1] += wgt * v0.y;
            a[2] += wgt * v0.z;  a[3] += wgt * v0.w;
            a[4] += wgt * v1.x;  a[5] += wgt * v1.y;
            a[6] += wgt * v1.z;  a[7] += wgt * v1.w;
        }
#pragma unroll
        for (int dd = 0; dd < 8; ++dd) so[lo * 4 + ia][h * 8 + dd] = a[dd] * inv;
    }
    __syncthreads();

    // out proj + residual (2 outputs/thread)
    {
        const int r2 = tid & 15;
        const int cB = tid >> 4;
        float orow[32];
#pragma unroll
        for (int k = 0; k < 32; ++k) orow[k] = so[r2][k];
#pragma unroll
        for (int i = 0; i < 2; ++i) {
            int c = cB + i * 16;
            const float4* wr4 = (const float4*)&w_out[c * 32];
            float acc = b_out[c] + sx[r2][c];
#pragma unroll
            for (int k4 = 0; k4 < 8; ++k4) {
                float4 wv = wr4[k4];
                acc += orow[k4 * 4 + 0] * wv.x + orow[k4 * 4 + 1] * wv.y +
                       orow[k4 * 4 + 2] * wv.z + orow[k4 * 4 + 3] * wv.w;
            }
            sqkv[r2 * 100 + c] = acc;
        }
    }
    __syncthreads();

    // LN normalize per row (pre-gamma) -> so
    {
        const int c = tid & 31;
#pragma unroll
        for (int p = 0; p < 2; ++p) {
            int r = p * 8 + (tid >> 5);
            float v = sqkv[r * 100 + c];
            float s1 = v;
#pragma unroll
            for (int off = 16; off >= 1; off >>= 1) s1 += __shfl_xor(s1, off, 64);
            float mu = s1 * (1.f / 32.f);
            float d = v - mu;
            float s2 = d * d;
#pragma unroll
            for (int off = 16; off >= 1; off >>= 1) s2 += __shfl_xor(s2, off, 64);
            float rstd = rsqrtf(s2 * (1.f / 32.f) + LN_EPS);
            so[r][c] = d * rstd;
        }
    }
    __syncthreads();

    // track mean (gamma/beta folded) + row norm via shuffle: 4 lo x 32 c
    if (tid < 128) {
        const int lo = tid >> 5, c = tid & 31;
        float mval = 0.25f * (so[lo * 4 + 0][c] + so[lo * 4 + 1][c] +
                              so[lo * 4 + 2][c] + so[lo * 4 + 3][c]) * ln_g[c] + ln_b[c];
        m_out[(b * 64 + l0 + lo) * 32 + c] = mval;
        float q2 = mval * mval;
#pragma unroll
        for (int off = 16; off >= 1; off >>= 1) q2 += __shfl_xor(q2, off, 64);
        if (c == 0) nrm_out[b * 64 + l0 + lo] = sqrtf(q2);
    }
}

// ---------------------------------------------------------------------------
// Kernel 3: pair features (measured 19.6 us standalone). 1024 x 256, (256,4).
// ---------------------------------------------------------------------------
__global__ __launch_bounds__(256, 4) void k_pair(
    const float* __restrict__ m, const float* __restrict__ nrm,
    const float* __restrict__ pw, const float* __restrict__ pb,
    const float* __restrict__ pg, const float* __restrict__ pbeta,
    float* __restrict__ out)
{
    __shared__ float smj[64][36];
    __shared__ float sT[4 * 520];
    __shared__ float snj[64];
    __shared__ float sbias[16], sgam[16], sbet[16];

    const int bx = blockIdx.x;
    const int b  = bx >> 4;
    const int i0 = (bx & 15) * 4;
    const int tid = threadIdx.x;
    const int lane = tid & 63, w = tid >> 6;

    const int rem0 = tid, rem1 = tid + 256;
    const float* pw0 = pw + (rem0 >> 5) * 1024 + (rem0 & 31);
    const float* pw1 = pw + (rem1 >> 5) * 1024 + (rem1 & 31);
    float w0[32], w1[32];
#pragma unroll
    for (int c = 0; c < 32; ++c) { w0[c] = pw0[c * 32]; w1[c] = pw1[c * 32]; }

    const float* mb = m + b * 2048;
    for (int n = tid; n < 2048; n += 256) smj[n >> 5][n & 31] = mb[n];
    if (tid < 64) snj[tid] = nrm[b * 64 + tid];
    if (tid < 16) {
        sbias[tid] = pb[tid];
        sgam[tid]  = pg[tid];
        sbet[tid]  = pbeta[tid];
    }
    __syncthreads();

#pragma unroll
    for (int il = 0; il < 4; ++il) {
        const float4* mr4 = (const float4*)&smj[i0 + il][0];
        float a0 = 0.f, a1 = 0.f;
#pragma unroll
        for (int c4 = 0; c4 < 8; ++c4) {
            float4 mv = mr4[c4];
            a0 += mv.x * w0[c4 * 4 + 0] + mv.y * w0[c4 * 4 + 1] +
                  mv.z * w0[c4 * 4 + 2] + mv.w * w0[c4 * 4 + 3];
            a1 += mv.x * w1[c4 * 4 + 0] + mv.y * w1[c4 * 4 + 1] +
                  mv.z * w1[c4 * 4 + 2] + mv.w * w1[c4 * 4 + 3];
        }
        sT[il * 520 + rem0] = a0;
        sT[il * 520 + rem1] = a1;
    }
    __syncthreads();

    const int j = lane;
    float mj[32];
    {
        const float4* mjp = (const float4*)&smj[j][0];
#pragma unroll
        for (int d4 = 0; d4 < 8; ++d4) {
            float4 t = mjp[d4];
            mj[d4 * 4 + 0] = t.x;  mj[d4 * 4 + 1] = t.y;
            mj[d4 * 4 + 2] = t.z;  mj[d4 * 4 + 3] = t.w;
        }
    }
    const float nj = snj[j];

    {
        const int il = w;
        const int ig = i0 + il;
        const float invn = 1.f / fmaxf(snj[ig] * nj, 1e-6f);
        float f[16];
#pragma unroll
        for (int cp = 0; cp < 16; ++cp) {
            const float4* tr = (const float4*)&sT[il * 520 + cp * 32];
            float acc = 0.f;
#pragma unroll
            for (int d4 = 0; d4 < 8; ++d4) {
                float4 tv = tr[d4];
                acc += tv.x * mj[d4 * 4 + 0] + tv.y * mj[d4 * 4 + 1] +
                       tv.z * mj[d4 * 4 + 2] + tv.w * mj[d4 * 4 + 3];
            }
            f[cp] = acc * invn + sbias[cp];
        }
        float mu = 0.f;
#pragma unroll
        for (int cp = 0; cp < 16; ++cp) mu += f[cp];
        mu *= (1.f / 16.f);
        float var = 0.f;
#pragma unroll
        for (int cp = 0; cp < 16; ++cp) { float d = f[cp] - mu; var += d * d; }
        var *= (1.f / 16.f);
        const float rstd = rsqrtf(var + LN_EPS);
#pragma unroll
        for (int cp = 0; cp < 16; ++cp) {
            float v = (f[cp] - mu) * rstd * sgam[cp] + sbet[cp];
            float sl = v / (1.f + __expf(-v));
            out[((b * 16 + cp) * 64 + ig) * 64 + j] = sl;
        }
    }
}

// ---------------------------------------------------------------------------
extern "C" void kernel_launch(void* const* d_in, const int* in_sizes, int n_in,
                              void* d_out, int out_size, void* d_ws, size_t ws_size,
                              hipStream_t stream) {
    const float* ctcf  = (const float*)d_in[0];
    const float* hac   = (const float*)d_in[1];
    const float* me1   = (const float*)d_in[2];
    const float* me3   = (const float*)d_in[3];
    const float* ew    = (const float*)d_in[4];
    const float* ebias = (const float*)d_in[5];
    const float* pe    = (const float*)d_in[6];
    const float* riw   = (const float*)d_in[7];
    const float* rib   = (const float*)d_in[8];
    const float* row_  = (const float*)d_in[9];
    const float* rob   = (const float*)d_in[10];
    const float* rlg   = (const float*)d_in[11];
    const float* rlb   = (const float*)d_in[12];
    const float* ciw   = (const float*)d_in[13];
    const float* cib   = (const float*)d_in[14];
    const float* cow   = (const float*)d_in[15];
    const float* cob   = (const float*)d_in[16];
    const float* clg   = (const float*)d_in[17];
    const float* clb   = (const float*)d_in[18];
    const float* pw    = (const float*)d_in[19];
    const float* pb    = (const float*)d_in[20];
    const float* pg    = (const float*)d_in[21];
    const float* pbt   = (const float*)d_in[22];

    float* outp = (float*)d_out;

    // msaR (2 MB) borrows d_out (16 MB): fully consumed by k_col before
    // k_pair writes out (serial stream). m + norms in ws (~528 KB).
    float* msaR = (float*)d_out;
    float* mbuf = (float*)d_ws;                  // 64*64*32 floats
    float* nbuf = mbuf + 64 * 64 * 32;           // 64*64 floats

    k_row<<<512, 512, 0, stream>>>(ctcf, hac, me1, me3, ew, ebias, pe,
                                   riw, rib, row_, rob, rlg, rlb, msaR);
    k_col<<<1024, 256, 0, stream>>>(msaR, ciw, cib, cow, cob, clg, clb,
                                    mbuf, nbuf);
    k_pair<<<1024, 256, 0, stream>>>(mbuf, nbuf, pw, pb, pg, pbt, outp);
}